// Round 3
// baseline (622.533 us; speedup 1.0000x reference)
//
#include <hip/hip_runtime.h>
#include <cstdint>

#define NEG_SLOPE 0.2f
#define LN_EPS 1e-5f

typedef __bf16 bf16x8 __attribute__((ext_vector_type(8)));
typedef float f32x4 __attribute__((ext_vector_type(4)));

__device__ __forceinline__ float b2f(unsigned int u) {
    union { unsigned int i; float f; } x; x.i = u << 16; return x.f;
}
__device__ __forceinline__ unsigned short f2b(float f) {
    union { float f; unsigned int i; } x; x.f = f;
    unsigned int r = x.i + 0x7fffu + ((x.i >> 16) & 1u);
    return (unsigned short)(r >> 16);
}

// ---------------- k0a: fold attention vectors into projections (all fp32) --------
__global__ void k0a_prep(const float* __restrict__ W,
                         const float* __restrict__ We,
                         const float* __restrict__ att_src,
                         const float* __restrict__ att_dst,
                         const float* __restrict__ att_edge,
                         float* __restrict__ u_src, float* __restrict__ u_dst,
                         float* __restrict__ vW) {
    int t = threadIdx.x;  // 256
    const float* wr = W + t * 256;
    for (int h = 0; h < 8; h++) {
        float s1 = 0.f, s2 = 0.f;
        for (int c = 0; c < 32; c++) {
            float w = wr[h * 32 + c];
            s1 += w * att_src[h * 32 + c];
            s2 += w * att_dst[h * 32 + c];
        }
        u_src[t * 8 + h] = s1; u_dst[t * 8 + h] = s2;
    }
    if (t < 64) {
        const float* er = We + t * 256;
        for (int h = 0; h < 8; h++) {
            float s = 0.f;
            for (int c = 0; c < 32; c++) s += er[h * 32 + c] * att_edge[h * 32 + c];
            vW[t * 8 + h] = s;
        }
    }
}

// ---------------- k0b: W -> bf16 fragment-order layout for coalesced MFMA B loads -
__global__ void k0b_wfrag(const float* __restrict__ W,
                          unsigned short* __restrict__ Wf) {
    int T = blockIdx.x * 256 + threadIdx.x;  // 65536 total
    int j    = T & 7;
    int lane = (T >> 3) & 63;
    int kk   = (T >> 9) & 7;
    int i    = (T >> 12) & 3;
    int w    = T >> 14;
    int n = w * 64 + i * 16 + (lane & 15);
    int k = kk * 32 + (lane >> 4) * 8 + j;
    Wf[T] = f2b(W[k * 256 + n]);
}

// ---------------- k1: xp = bf16(x) @ bf16(W) via MFMA; fused a_src/a_dst ----------
__global__ __launch_bounds__(256) void k1_xp(const float* __restrict__ x,
                                             const unsigned short* __restrict__ Wf,
                                             const float* __restrict__ u_src,
                                             const float* __restrict__ u_dst,
                                             unsigned short* __restrict__ xp,
                                             float* __restrict__ a_src,
                                             float* __restrict__ a_dst, int N) {
    __shared__ float red[2][4][16][8];  // [arr][wave][row][head] = 4 KB
    int m0 = blockIdx.x * 16;
    int lane = threadIdx.x & 63, wave = threadIdx.x >> 6;
    int quad = lane >> 4, l16 = lane & 15;
    int mrow = m0 + l16; if (mrow > N - 1) mrow = N - 1;
    const float* ap = x + (size_t)mrow * 256 + quad * 8;
    const unsigned short* wfw = Wf + (size_t)wave * 16384;
    f32x4 ac0 = {0,0,0,0}, ac1 = {0,0,0,0}, ac2 = {0,0,0,0}, ac3 = {0,0,0,0};
    float pas[8] = {0,0,0,0,0,0,0,0}, pad_[8] = {0,0,0,0,0,0,0,0};
#pragma unroll
    for (int kk = 0; kk < 8; kk++) {
        float4 fa0 = *(const float4*)(ap + kk * 32);
        float4 fa1 = *(const float4*)(ap + kk * 32 + 4);
        if ((kk >> 1) == wave) {
            float f[8] = {fa0.x, fa0.y, fa0.z, fa0.w, fa1.x, fa1.y, fa1.z, fa1.w};
#pragma unroll
            for (int j = 0; j < 8; j++) {
                int k = kk * 32 + quad * 8 + j;
                const float4* up = (const float4*)(u_src + k * 8);
                float4 s0 = up[0], s1 = up[1];
                const float4* vp = (const float4*)(u_dst + k * 8);
                float4 d0 = vp[0], d1 = vp[1];
                pas[0] += f[j] * s0.x; pas[1] += f[j] * s0.y;
                pas[2] += f[j] * s0.z; pas[3] += f[j] * s0.w;
                pas[4] += f[j] * s1.x; pas[5] += f[j] * s1.y;
                pas[6] += f[j] * s1.z; pas[7] += f[j] * s1.w;
                pad_[0] += f[j] * d0.x; pad_[1] += f[j] * d0.y;
                pad_[2] += f[j] * d0.z; pad_[3] += f[j] * d0.w;
                pad_[4] += f[j] * d1.x; pad_[5] += f[j] * d1.y;
                pad_[6] += f[j] * d1.z; pad_[7] += f[j] * d1.w;
            }
        }
        union { unsigned short u[8]; bf16x8 v; } A;
        A.u[0] = f2b(fa0.x); A.u[1] = f2b(fa0.y); A.u[2] = f2b(fa0.z); A.u[3] = f2b(fa0.w);
        A.u[4] = f2b(fa1.x); A.u[5] = f2b(fa1.y); A.u[6] = f2b(fa1.z); A.u[7] = f2b(fa1.w);
        const unsigned short* wk = wfw + kk * 512 + lane * 8;  // coalesced 1KB/wave
        bf16x8 b0 = *(const bf16x8*)(wk);
        bf16x8 b1 = *(const bf16x8*)(wk + 4096);
        bf16x8 b2 = *(const bf16x8*)(wk + 8192);
        bf16x8 b3 = *(const bf16x8*)(wk + 12288);
        ac0 = __builtin_amdgcn_mfma_f32_16x16x32_bf16(A.v, b0, ac0, 0, 0, 0);
        ac1 = __builtin_amdgcn_mfma_f32_16x16x32_bf16(A.v, b1, ac1, 0, 0, 0);
        ac2 = __builtin_amdgcn_mfma_f32_16x16x32_bf16(A.v, b2, ac2, 0, 0, 0);
        ac3 = __builtin_amdgcn_mfma_f32_16x16x32_bf16(A.v, b3, ac3, 0, 0, 0);
    }
#pragma unroll
    for (int h = 0; h < 8; h++) {
        pas[h] += __shfl_xor(pas[h], 16, 64);
        pas[h] += __shfl_xor(pas[h], 32, 64);
        pad_[h] += __shfl_xor(pad_[h], 16, 64);
        pad_[h] += __shfl_xor(pad_[h], 32, 64);
    }
    if (quad == 0) {
#pragma unroll
        for (int h = 0; h < 8; h++) {
            red[0][wave][l16][h] = pas[h];
            red[1][wave][l16][h] = pad_[h];
        }
    }
    int nb = wave * 64;
#pragma unroll
    for (int r = 0; r < 4; r++) {
        int m = m0 + quad * 4 + r;
        if (m < N) {
            unsigned short* op = xp + (size_t)m * 256 + nb + l16;
            op[0]  = f2b(ac0[r]); op[16] = f2b(ac1[r]);
            op[32] = f2b(ac2[r]); op[48] = f2b(ac3[r]);
        }
    }
    __syncthreads();
    {
        int t = threadIdx.x;
        int arr = t >> 7, r = (t >> 3) & 15, h = t & 7;
        int m = m0 + r;
        if (m < N) {
            float sum = red[arr][0][r][h] + red[arr][1][r][h]
                      + red[arr][2][r][h] + red[arr][3][r][h];
            (arr ? a_dst : a_src)[m * 8 + h] = sum;
        }
    }
}

// ---------------- k2: per-edge logits + exp; 4 lanes per edge, coalesced ----------
__global__ __launch_bounds__(256) void k2_edge(const int* __restrict__ ei,
                                               const float* __restrict__ eattr,
                                               const float* __restrict__ vW,
                                               const float* __restrict__ a_src,
                                               const float* __restrict__ a_dst,
                                               unsigned short* __restrict__ ea,
                                               int* __restrict__ deg, int E) {
    __shared__ float sv[2048];  // vW bank-permuted: row kl = ((k&15)<<2)|(k>>4)
    int t = threadIdx.x;
    if (t < 128) {  // vW = 64 rows x 8 heads = 128 float4s
        const float4* g = (const float4*)vW;
        float4* s4 = (float4*)sv;
        int k = t >> 1, half = t & 1;
        int kl = ((k & 15) << 2) | (k >> 4);
        s4[kl * 2 + half] = g[t];
    }
    __syncthreads();
    int e = blockIdx.x * 64 + (t >> 2), kp = t & 3;
    if (e >= E) return;
    const float4* ar = (const float4*)(eattr + (size_t)e * 64 + kp * 16);
    float acc[8] = {0,0,0,0,0,0,0,0};
#pragma unroll
    for (int q = 0; q < 4; q++) {
        float4 u = ar[q];
        float f[4] = {u.x, u.y, u.z, u.w};
#pragma unroll
        for (int j = 0; j < 4; j++) {
            int kl = ((q * 4 + j) << 2) | kp;
            const float4* vp = (const float4*)(sv + kl * 8);
            float4 v0 = vp[0], v1 = vp[1];
            acc[0] += f[j] * v0.x; acc[1] += f[j] * v0.y;
            acc[2] += f[j] * v0.z; acc[3] += f[j] * v0.w;
            acc[4] += f[j] * v1.x; acc[5] += f[j] * v1.y;
            acc[6] += f[j] * v1.z; acc[7] += f[j] * v1.w;
        }
    }
#pragma unroll
    for (int h = 0; h < 8; h++) {
        acc[h] += __shfl_xor(acc[h], 1, 64);
        acc[h] += __shfl_xor(acc[h], 2, 64);
    }
    int s = ei[e], d = ei[E + e];
    float2 asv = *(const float2*)(a_src + s * 8 + kp * 2);
    float2 adv = *(const float2*)(a_dst + d * 8 + kp * 2);
    float l0 = asv.x + adv.x + acc[kp * 2];
    float l1 = asv.y + adv.y + acc[kp * 2 + 1];
    l0 = (l0 > 0.f) ? l0 : NEG_SLOPE * l0;
    l1 = (l1 > 0.f) ? l1 : NEG_SLOPE * l1;
    unsigned int pk = (unsigned)f2b(__expf(l0)) | ((unsigned)f2b(__expf(l1)) << 16);
    ((unsigned int*)ea)[(size_t)e * 4 + kp] = pk;
    if (kp == 0) atomicAdd(deg + d, 1);
}

// ---------------- k3: 3-phase exclusive scan of degrees -> CSR rowptr --------------
__global__ __launch_bounds__(1024) void k3a_scan(const int* __restrict__ deg,
                                                 int* __restrict__ rowptr,
                                                 int* __restrict__ bsum, int N) {
    __shared__ int s[1024];
    int t = threadIdx.x, i = blockIdx.x * 1024 + t;
    int v = (i < N) ? deg[i] : 0;
    s[t] = v; __syncthreads();
    for (int off = 1; off < 1024; off <<= 1) {
        int add = (t >= off) ? s[t - off] : 0;
        __syncthreads();
        s[t] += add;
        __syncthreads();
    }
    if (i < N) rowptr[i] = s[t] - v;
    if (t == 1023) bsum[blockIdx.x] = s[1023];
}
// parallel wave scan (nb <= 64)
__global__ void k3b_scan(const int* __restrict__ bsum, int* __restrict__ boff, int nb) {
    int l = threadIdx.x;  // 64
    int v = (l < nb) ? bsum[l] : 0;
    int x = v;
#pragma unroll
    for (int off = 1; off < 64; off <<= 1) {
        int y = __shfl_up(x, off, 64);
        if (l >= off) x += y;
    }
    if (l < nb) boff[l] = x - v;
}
__global__ __launch_bounds__(1024) void k3c_add(int* __restrict__ rowptr,
                                                int* __restrict__ cursor,
                                                const int* __restrict__ boff, int N, int E) {
    int i = blockIdx.x * 1024 + threadIdx.x;
    if (i < N) {
        int r = rowptr[i] + boff[blockIdx.x];
        rowptr[i] = r; cursor[i] = r;
    }
    if (i == 0) rowptr[N] = E;
}
__global__ __launch_bounds__(256) void k3d_scatter(const int* __restrict__ ei,
                                                   int* __restrict__ cursor,
                                                   int* __restrict__ perm, int E) {
    int e = blockIdx.x * 256 + threadIdx.x;
    if (e >= E) return;
    int d = ei[E + e];
    int p = atomicAdd(cursor + d, 1);
    perm[p] = e;
}

// ---------------- k4: SINGLE-pass gather (normalize at end) + bias + res + LN -----
// 4 waves/block; wave 0 stages edges + accumulates den; waves split edge list 4-way.
__global__ __launch_bounds__(256) void k4_agg(const float* __restrict__ xin,
                                              const unsigned short* __restrict__ xp,
                                              const unsigned short* __restrict__ ea,
                                              const int* __restrict__ rowptr,
                                              const int* __restrict__ perm,
                                              const int* __restrict__ ei,
                                              const float* __restrict__ bias,
                                              const float* __restrict__ gamma,
                                              const float* __restrict__ beta,
                                              float* __restrict__ out, int N) {
    __shared__ int ssrc[64];
    __shared__ float sea[64 * 9];       // raw exp values, pad 8->9
    __shared__ float racc[4][64][4];    // per-wave partial messages
    __shared__ float rden[8];
    int n = blockIdx.x;
    int t = threadIdx.x, wave = t >> 6, l = t & 63;
    int start = rowptr[n], end = rowptr[n + 1];
    int hh = l >> 3;
    float a0 = 0.f, a1 = 0.f, a2 = 0.f, a3 = 0.f;
    float den[8] = {0,0,0,0,0,0,0,0};   // only wave 0 accumulates (t<cnt<=64)
    for (int base = start; base < end; base += 64) {
        int cnt = end - base; if (cnt > 64) cnt = 64;
        if (t < cnt) {
            int e = perm[base + t];
            ssrc[t] = ei[e];
            uint4 u = ((const uint4*)ea)[e];
            float v0 = b2f(u.x & 0xffffu), v1 = b2f(u.x >> 16);
            float v2 = b2f(u.y & 0xffffu), v3 = b2f(u.y >> 16);
            float v4 = b2f(u.z & 0xffffu), v5 = b2f(u.z >> 16);
            float v6 = b2f(u.w & 0xffffu), v7 = b2f(u.w >> 16);
            float* sp = sea + t * 9;
            sp[0] = v0; sp[1] = v1; sp[2] = v2; sp[3] = v3;
            sp[4] = v4; sp[5] = v5; sp[6] = v6; sp[7] = v7;
            den[0] += v0; den[1] += v1; den[2] += v2; den[3] += v3;
            den[4] += v4; den[5] += v5; den[6] += v6; den[7] += v7;
        }
        __syncthreads();
        for (int i = wave; i < cnt; i += 4) {
            int s = ssrc[i];
            uint2 u = *(const uint2*)(xp + (size_t)s * 256 + l * 4);
            float w = sea[i * 9 + hh];
            a0 += b2f(u.x & 0xffffu) * w; a1 += b2f(u.x >> 16) * w;
            a2 += b2f(u.y & 0xffffu) * w; a3 += b2f(u.y >> 16) * w;
        }
        __syncthreads();
    }
    racc[wave][l][0] = a0; racc[wave][l][1] = a1;
    racc[wave][l][2] = a2; racc[wave][l][3] = a3;
    if (wave == 0) {
#pragma unroll
        for (int off = 32; off > 0; off >>= 1) {
#pragma unroll
            for (int j = 0; j < 8; j++) den[j] += __shfl_xor(den[j], off, 64);
        }
        if (l < 8) rden[l] = den[l];
    }
    __syncthreads();
    if (wave != 0) return;  // no further barriers below
    float m0 = racc[0][l][0] + racc[1][l][0] + racc[2][l][0] + racc[3][l][0];
    float m1 = racc[0][l][1] + racc[1][l][1] + racc[2][l][1] + racc[3][l][1];
    float m2 = racc[0][l][2] + racc[1][l][2] + racc[2][l][2] + racc[3][l][2];
    float m3 = racc[0][l][3] + racc[1][l][3] + racc[2][l][3] + racc[3][l][3];
    float sinv = 1.0f / (rden[hh] + 1e-16f);
    m0 *= sinv; m1 *= sinv; m2 *= sinv; m3 *= sinv;
    float4 xv = *(const float4*)(xin + (size_t)n * 256 + l * 4);
    float4 bv = *(const float4*)(bias + l * 4);
    float y0 = xv.x + m0 + bv.x;
    float y1 = xv.y + m1 + bv.y;
    float y2 = xv.z + m2 + bv.z;
    float y3 = xv.w + m3 + bv.w;
    float s1 = y0 + y1 + y2 + y3;
    float s2 = y0 * y0 + y1 * y1 + y2 * y2 + y3 * y3;
#pragma unroll
    for (int o = 32; o > 0; o >>= 1) {
        s1 += __shfl_down(s1, o, 64);
        s2 += __shfl_down(s2, o, 64);
    }
    s1 = __shfl(s1, 0, 64); s2 = __shfl(s2, 0, 64);
    float mu = s1 * (1.f / 256.f);
    float var = s2 * (1.f / 256.f) - mu * mu;
    float rs = rsqrtf(var + LN_EPS);
    float4 gv  = *(const float4*)(gamma + l * 4);
    float4 btv = *(const float4*)(beta + l * 4);
    float4 ov;
    ov.x = (y0 - mu) * rs * gv.x + btv.x;
    ov.y = (y1 - mu) * rs * gv.y + btv.y;
    ov.z = (y2 - mu) * rs * gv.z + btv.z;
    ov.w = (y3 - mu) * rs * gv.w + btv.w;
    *(float4*)(out + (size_t)n * 256 + l * 4) = ov;
}

extern "C" void kernel_launch(void* const* d_in, const int* in_sizes, int n_in,
                              void* d_out, int out_size, void* d_ws, size_t ws_size,
                              hipStream_t stream) {
    const float* x     = (const float*)d_in[0];
    const int*   ei    = (const int*)d_in[1];
    const float* eattr = (const float*)d_in[2];
    const float* W     = (const float*)d_in[3];
    const float* We    = (const float*)d_in[4];
    const float* atts  = (const float*)d_in[5];
    const float* attd  = (const float*)d_in[6];
    const float* atte  = (const float*)d_in[7];
    const float* bias  = (const float*)d_in[8];
    const float* gamma = (const float*)d_in[9];
    const float* beta  = (const float*)d_in[10];
    float* out = (float*)d_out;
    int N = in_sizes[0] / 256;
    int E = in_sizes[1] / 2;

    char* p = (char*)d_ws;
    auto carve = [&](size_t bytes) -> void* {
        void* r = (void*)p; p += (bytes + 255) & ~(size_t)255; return r;
    };
    unsigned short* xp = (unsigned short*)carve((size_t)N * 256 * 2);  // bf16
    unsigned short* ea = (unsigned short*)carve((size_t)E * 8 * 2);    // bf16
    float* a_src       = (float*)carve((size_t)N * 8 * 4);
    float* a_dst       = (float*)carve((size_t)N * 8 * 4);
    int*   deg         = (int*)carve((size_t)N * 4);
    int*   rowptr      = (int*)carve((size_t)(N + 1) * 4);
    int*   cursor      = (int*)carve((size_t)N * 4);
    int*   perm        = (int*)carve((size_t)E * 4);
    int*   bsum        = (int*)carve(1024);
    int*   boff        = (int*)carve(1024);
    float* u_src       = (float*)carve(2048 * 4);
    float* u_dst       = (float*)carve(2048 * 4);
    float* vW          = (float*)carve(512 * 4);
    unsigned short* Wf = (unsigned short*)carve(65536 * 2);

    hipMemsetAsync(deg, 0, (size_t)N * 4, stream);

    hipLaunchKernelGGL(k0a_prep, dim3(1), dim3(256), 0, stream,
                       W, We, atts, attd, atte, u_src, u_dst, vW);
    hipLaunchKernelGGL(k0b_wfrag, dim3(256), dim3(256), 0, stream, W, Wf);
    hipLaunchKernelGGL(k1_xp, dim3((N + 15) / 16), dim3(256), 0, stream,
                       x, Wf, u_src, u_dst, xp, a_src, a_dst, N);
    hipLaunchKernelGGL(k2_edge, dim3((E + 63) / 64), dim3(256), 0, stream,
                       ei, eattr, vW, a_src, a_dst, ea, deg, E);
    int nb = (N + 1023) / 1024;
    hipLaunchKernelGGL(k3a_scan, dim3(nb), dim3(1024), 0, stream, deg, rowptr, bsum, N);
    hipLaunchKernelGGL(k3b_scan, dim3(1), dim3(64), 0, stream, bsum, boff, nb);
    hipLaunchKernelGGL(k3c_add, dim3(nb), dim3(1024), 0, stream, rowptr, cursor, boff, N, E);
    hipLaunchKernelGGL(k3d_scatter, dim3((E + 255) / 256), dim3(256), 0, stream,
                       ei, cursor, perm, E);
    hipLaunchKernelGGL(k4_agg, dim3(N), dim3(256), 0, stream,
                       x, xp, ea, rowptr, perm, ei, bias, gamma, beta, out, N);
}

// Round 4
// 610.573 us; speedup vs baseline: 1.0196x; 1.0196x over previous
//
#include <hip/hip_runtime.h>
#include <cstdint>

#define NEG_SLOPE 0.2f
#define LN_EPS 1e-5f

typedef __bf16 bf16x8 __attribute__((ext_vector_type(8)));
typedef float f32x4 __attribute__((ext_vector_type(4)));

__device__ __forceinline__ float b2f(unsigned int u) {
    union { unsigned int i; float f; } x; x.i = u << 16; return x.f;
}
__device__ __forceinline__ unsigned short f2b(float f) {
    union { float f; unsigned int i; } x; x.f = f;
    unsigned int r = x.i + 0x7fffu + ((x.i >> 16) & 1u);
    return (unsigned short)(r >> 16);
}

// ---------------- k0a: fold attention vectors into projections (all fp32) --------
__global__ void k0a_prep(const float* __restrict__ W,
                         const float* __restrict__ We,
                         const float* __restrict__ att_src,
                         const float* __restrict__ att_dst,
                         const float* __restrict__ att_edge,
                         float* __restrict__ u_src, float* __restrict__ u_dst,
                         float* __restrict__ vW) {
    int t = threadIdx.x;  // 256
    const float* wr = W + t * 256;
    for (int h = 0; h < 8; h++) {
        float s1 = 0.f, s2 = 0.f;
        for (int c = 0; c < 32; c++) {
            float w = wr[h * 32 + c];
            s1 += w * att_src[h * 32 + c];
            s2 += w * att_dst[h * 32 + c];
        }
        u_src[t * 8 + h] = s1; u_dst[t * 8 + h] = s2;
    }
    if (t < 64) {
        const float* er = We + t * 256;
        for (int h = 0; h < 8; h++) {
            float s = 0.f;
            for (int c = 0; c < 32; c++) s += er[h * 32 + c] * att_edge[h * 32 + c];
            vW[t * 8 + h] = s;
        }
    }
}

// ---------------- k0b: W -> bf16 fragment-order layout for coalesced MFMA B loads -
__global__ void k0b_wfrag(const float* __restrict__ W,
                          unsigned short* __restrict__ Wf) {
    int T = blockIdx.x * 256 + threadIdx.x;  // 65536 total
    int j    = T & 7;
    int lane = (T >> 3) & 63;
    int kk   = (T >> 9) & 7;
    int i    = (T >> 12) & 3;
    int w    = T >> 14;
    int n = w * 64 + i * 16 + (lane & 15);
    int k = kk * 32 + (lane >> 4) * 8 + j;
    Wf[T] = f2b(W[k * 256 + n]);
}

// ---------------- k_deg: degree histogram (dst) ------------------------------------
__global__ __launch_bounds__(256) void k_deg(const int* __restrict__ ei,
                                             int* __restrict__ deg, int E) {
    int e = blockIdx.x * 256 + threadIdx.x;
    if (e < E) atomicAdd(deg + ei[E + e], 1);
}

// ---------------- k1: xp = bf16(x) @ bf16(W) via MFMA; fused a_src/a_dst ----------
__global__ __launch_bounds__(256) void k1_xp(const float* __restrict__ x,
                                             const unsigned short* __restrict__ Wf,
                                             const float* __restrict__ u_src,
                                             const float* __restrict__ u_dst,
                                             unsigned short* __restrict__ xp,
                                             float* __restrict__ a_src,
                                             float* __restrict__ a_dst, int N) {
    __shared__ float red[2][4][16][8];  // [arr][wave][row][head] = 4 KB
    int m0 = blockIdx.x * 16;
    int lane = threadIdx.x & 63, wave = threadIdx.x >> 6;
    int quad = lane >> 4, l16 = lane & 15;
    int mrow = m0 + l16; if (mrow > N - 1) mrow = N - 1;
    const float* ap = x + (size_t)mrow * 256 + quad * 8;
    const unsigned short* wfw = Wf + (size_t)wave * 16384;
    f32x4 ac0 = {0,0,0,0}, ac1 = {0,0,0,0}, ac2 = {0,0,0,0}, ac3 = {0,0,0,0};
    float pas[8] = {0,0,0,0,0,0,0,0}, pad_[8] = {0,0,0,0,0,0,0,0};
#pragma unroll
    for (int kk = 0; kk < 8; kk++) {
        float4 fa0 = *(const float4*)(ap + kk * 32);
        float4 fa1 = *(const float4*)(ap + kk * 32 + 4);
        if ((kk >> 1) == wave) {
            float f[8] = {fa0.x, fa0.y, fa0.z, fa0.w, fa1.x, fa1.y, fa1.z, fa1.w};
#pragma unroll
            for (int j = 0; j < 8; j++) {
                int k = kk * 32 + quad * 8 + j;
                const float4* up = (const float4*)(u_src + k * 8);
                float4 s0 = up[0], s1 = up[1];
                const float4* vp = (const float4*)(u_dst + k * 8);
                float4 d0 = vp[0], d1 = vp[1];
                pas[0] += f[j] * s0.x; pas[1] += f[j] * s0.y;
                pas[2] += f[j] * s0.z; pas[3] += f[j] * s0.w;
                pas[4] += f[j] * s1.x; pas[5] += f[j] * s1.y;
                pas[6] += f[j] * s1.z; pas[7] += f[j] * s1.w;
                pad_[0] += f[j] * d0.x; pad_[1] += f[j] * d0.y;
                pad_[2] += f[j] * d0.z; pad_[3] += f[j] * d0.w;
                pad_[4] += f[j] * d1.x; pad_[5] += f[j] * d1.y;
                pad_[6] += f[j] * d1.z; pad_[7] += f[j] * d1.w;
            }
        }
        union { unsigned short u[8]; bf16x8 v; } A;
        A.u[0] = f2b(fa0.x); A.u[1] = f2b(fa0.y); A.u[2] = f2b(fa0.z); A.u[3] = f2b(fa0.w);
        A.u[4] = f2b(fa1.x); A.u[5] = f2b(fa1.y); A.u[6] = f2b(fa1.z); A.u[7] = f2b(fa1.w);
        const unsigned short* wk = wfw + kk * 512 + lane * 8;  // coalesced 1KB/wave
        bf16x8 b0 = *(const bf16x8*)(wk);
        bf16x8 b1 = *(const bf16x8*)(wk + 4096);
        bf16x8 b2 = *(const bf16x8*)(wk + 8192);
        bf16x8 b3 = *(const bf16x8*)(wk + 12288);
        ac0 = __builtin_amdgcn_mfma_f32_16x16x32_bf16(A.v, b0, ac0, 0, 0, 0);
        ac1 = __builtin_amdgcn_mfma_f32_16x16x32_bf16(A.v, b1, ac1, 0, 0, 0);
        ac2 = __builtin_amdgcn_mfma_f32_16x16x32_bf16(A.v, b2, ac2, 0, 0, 0);
        ac3 = __builtin_amdgcn_mfma_f32_16x16x32_bf16(A.v, b3, ac3, 0, 0, 0);
    }
#pragma unroll
    for (int h = 0; h < 8; h++) {
        pas[h] += __shfl_xor(pas[h], 16, 64);
        pas[h] += __shfl_xor(pas[h], 32, 64);
        pad_[h] += __shfl_xor(pad_[h], 16, 64);
        pad_[h] += __shfl_xor(pad_[h], 32, 64);
    }
    if (quad == 0) {
#pragma unroll
        for (int h = 0; h < 8; h++) {
            red[0][wave][l16][h] = pas[h];
            red[1][wave][l16][h] = pad_[h];
        }
    }
    int nb = wave * 64;
#pragma unroll
    for (int r = 0; r < 4; r++) {
        int m = m0 + quad * 4 + r;
        if (m < N) {
            unsigned short* op = xp + (size_t)m * 256 + nb + l16;
            op[0]  = f2b(ac0[r]); op[16] = f2b(ac1[r]);
            op[32] = f2b(ac2[r]); op[48] = f2b(ac3[r]);
        }
    }
    __syncthreads();
    {
        int t = threadIdx.x;
        int arr = t >> 7, r = (t >> 3) & 15, h = t & 7;
        int m = m0 + r;
        if (m < N) {
            float sum = red[arr][0][r][h] + red[arr][1][r][h]
                      + red[arr][2][r][h] + red[arr][3][r][h];
            (arr ? a_dst : a_src)[m * 8 + h] = sum;
        }
    }
}

// ---------------- k2: per-edge logits + exp; scatter packed CSR records -----------
__global__ __launch_bounds__(256) void k2_edge(const int* __restrict__ ei,
                                               const float* __restrict__ eattr,
                                               const float* __restrict__ vW,
                                               const float* __restrict__ a_src,
                                               const float* __restrict__ a_dst,
                                               int* __restrict__ cursor,
                                               int* __restrict__ srcs,
                                               uint4* __restrict__ eav, int E) {
    __shared__ float sv[2048];  // vW bank-permuted: row kl = ((k&15)<<2)|(k>>4)
    int t = threadIdx.x;
    if (t < 128) {  // vW = 64 rows x 8 heads = 128 float4s
        const float4* g = (const float4*)vW;
        float4* s4 = (float4*)sv;
        int k = t >> 1, half = t & 1;
        int kl = ((k & 15) << 2) | (k >> 4);
        s4[kl * 2 + half] = g[t];
    }
    __syncthreads();
    int e = blockIdx.x * 64 + (t >> 2), kp = t & 3;
    if (e >= E) return;
    const float4* ar = (const float4*)(eattr + (size_t)e * 64 + kp * 16);
    float acc[8] = {0,0,0,0,0,0,0,0};
#pragma unroll
    for (int q = 0; q < 4; q++) {
        float4 u = ar[q];
        float f[4] = {u.x, u.y, u.z, u.w};
#pragma unroll
        for (int j = 0; j < 4; j++) {
            int kl = ((q * 4 + j) << 2) | kp;
            const float4* vp = (const float4*)(sv + kl * 8);
            float4 v0 = vp[0], v1 = vp[1];
            acc[0] += f[j] * v0.x; acc[1] += f[j] * v0.y;
            acc[2] += f[j] * v0.z; acc[3] += f[j] * v0.w;
            acc[4] += f[j] * v1.x; acc[5] += f[j] * v1.y;
            acc[6] += f[j] * v1.z; acc[7] += f[j] * v1.w;
        }
    }
#pragma unroll
    for (int h = 0; h < 8; h++) {
        acc[h] += __shfl_xor(acc[h], 1, 64);
        acc[h] += __shfl_xor(acc[h], 2, 64);
    }
    int s = ei[e], d = ei[E + e];
    float2 asv = *(const float2*)(a_src + s * 8 + kp * 2);
    float2 adv = *(const float2*)(a_dst + d * 8 + kp * 2);
    float l0 = asv.x + adv.x + acc[kp * 2];
    float l1 = asv.y + adv.y + acc[kp * 2 + 1];
    l0 = (l0 > 0.f) ? l0 : NEG_SLOPE * l0;
    l1 = (l1 > 0.f) ? l1 : NEG_SLOPE * l1;
    unsigned int pk = (unsigned)f2b(__expf(l0)) | ((unsigned)f2b(__expf(l1)) << 16);
    int l = t & 63;
    int p = 0;
    if (kp == 0) p = atomicAdd(cursor + d, 1);
    p = __shfl(p, l & 60, 64);              // broadcast slot within 4-lane group
    ((unsigned int*)eav)[(size_t)p * 4 + kp] = pk;
    if (kp == 0) srcs[p] = s;
}

// ---------------- k3: 3-phase exclusive scan of degrees -> CSR rowptr --------------
__global__ __launch_bounds__(1024) void k3a_scan(const int* __restrict__ deg,
                                                 int* __restrict__ rowptr,
                                                 int* __restrict__ bsum, int N) {
    __shared__ int s[1024];
    int t = threadIdx.x, i = blockIdx.x * 1024 + t;
    int v = (i < N) ? deg[i] : 0;
    s[t] = v; __syncthreads();
    for (int off = 1; off < 1024; off <<= 1) {
        int add = (t >= off) ? s[t - off] : 0;
        __syncthreads();
        s[t] += add;
        __syncthreads();
    }
    if (i < N) rowptr[i] = s[t] - v;
    if (t == 1023) bsum[blockIdx.x] = s[1023];
}
// parallel wave scan (nb <= 64)
__global__ void k3b_scan(const int* __restrict__ bsum, int* __restrict__ boff, int nb) {
    int l = threadIdx.x;  // 64
    int v = (l < nb) ? bsum[l] : 0;
    int x = v;
#pragma unroll
    for (int off = 1; off < 64; off <<= 1) {
        int y = __shfl_up(x, off, 64);
        if (l >= off) x += y;
    }
    if (l < nb) boff[l] = x - v;
}
__global__ __launch_bounds__(1024) void k3c_add(int* __restrict__ rowptr,
                                                int* __restrict__ cursor,
                                                const int* __restrict__ boff, int N, int E) {
    int i = blockIdx.x * 1024 + threadIdx.x;
    if (i < N) {
        int r = rowptr[i] + boff[blockIdx.x];
        rowptr[i] = r; cursor[i] = r;
    }
    if (i == 0) rowptr[N] = E;
}

// ---------------- k4: sequential staged records + 4-deep unrolled gather + LN -----
__global__ __launch_bounds__(256) void k4_agg(const float* __restrict__ xin,
                                              const unsigned short* __restrict__ xp,
                                              const int* __restrict__ srcs,
                                              const uint4* __restrict__ eav,
                                              const int* __restrict__ rowptr,
                                              const float* __restrict__ bias,
                                              const float* __restrict__ gamma,
                                              const float* __restrict__ beta,
                                              float* __restrict__ out, int N) {
    __shared__ int ssrc[64];
    __shared__ float sea[64 * 9];       // raw exp values, pad 8->9
    __shared__ float racc[4][64][4];    // per-wave partial messages
    __shared__ float rden[8];
    int n = blockIdx.x;
    int t = threadIdx.x, wave = t >> 6, l = t & 63;
    int start = rowptr[n], end = rowptr[n + 1];
    int hh = l >> 3;
    float a0 = 0.f, a1 = 0.f, a2 = 0.f, a3 = 0.f;
    float den[8] = {0,0,0,0,0,0,0,0};   // only wave-0 lanes (t<cnt<=64) accumulate
    for (int base = start; base < end; base += 64) {
        int cnt = end - base; if (cnt > 64) cnt = 64;
        if (t < cnt) {
            ssrc[t] = srcs[base + t];              // coalesced
            uint4 u = eav[base + t];               // coalesced
            float v0 = b2f(u.x & 0xffffu), v1 = b2f(u.x >> 16);
            float v2 = b2f(u.y & 0xffffu), v3 = b2f(u.y >> 16);
            float v4 = b2f(u.z & 0xffffu), v5 = b2f(u.z >> 16);
            float v6 = b2f(u.w & 0xffffu), v7 = b2f(u.w >> 16);
            float* sp = sea + t * 9;
            sp[0] = v0; sp[1] = v1; sp[2] = v2; sp[3] = v3;
            sp[4] = v4; sp[5] = v5; sp[6] = v6; sp[7] = v7;
            den[0] += v0; den[1] += v1; den[2] += v2; den[3] += v3;
            den[4] += v4; den[5] += v5; den[6] += v6; den[7] += v7;
        }
        __syncthreads();
        int i = wave;
        // 4-deep: issue 4 independent gathers before consuming
        for (; i + 12 < cnt; i += 16) {
            int s0 = ssrc[i], s1 = ssrc[i + 4], s2 = ssrc[i + 8], s3 = ssrc[i + 12];
            uint2 u0 = *(const uint2*)(xp + (size_t)s0 * 256 + l * 4);
            uint2 u1 = *(const uint2*)(xp + (size_t)s1 * 256 + l * 4);
            uint2 u2 = *(const uint2*)(xp + (size_t)s2 * 256 + l * 4);
            uint2 u3 = *(const uint2*)(xp + (size_t)s3 * 256 + l * 4);
            float w0 = sea[i * 9 + hh],        w1 = sea[(i + 4) * 9 + hh];
            float w2 = sea[(i + 8) * 9 + hh],  w3 = sea[(i + 12) * 9 + hh];
            a0 += b2f(u0.x & 0xffffu) * w0; a1 += b2f(u0.x >> 16) * w0;
            a2 += b2f(u0.y & 0xffffu) * w0; a3 += b2f(u0.y >> 16) * w0;
            a0 += b2f(u1.x & 0xffffu) * w1; a1 += b2f(u1.x >> 16) * w1;
            a2 += b2f(u1.y & 0xffffu) * w1; a3 += b2f(u1.y >> 16) * w1;
            a0 += b2f(u2.x & 0xffffu) * w2; a1 += b2f(u2.x >> 16) * w2;
            a2 += b2f(u2.y & 0xffffu) * w2; a3 += b2f(u2.y >> 16) * w2;
            a0 += b2f(u3.x & 0xffffu) * w3; a1 += b2f(u3.x >> 16) * w3;
            a2 += b2f(u3.y & 0xffffu) * w3; a3 += b2f(u3.y >> 16) * w3;
        }
        // 2-deep residual
        for (; i + 4 < cnt; i += 8) {
            int s0 = ssrc[i], s1 = ssrc[i + 4];
            uint2 u0 = *(const uint2*)(xp + (size_t)s0 * 256 + l * 4);
            uint2 u1 = *(const uint2*)(xp + (size_t)s1 * 256 + l * 4);
            float w0 = sea[i * 9 + hh], w1 = sea[(i + 4) * 9 + hh];
            a0 += b2f(u0.x & 0xffffu) * w0; a1 += b2f(u0.x >> 16) * w0;
            a2 += b2f(u0.y & 0xffffu) * w0; a3 += b2f(u0.y >> 16) * w0;
            a0 += b2f(u1.x & 0xffffu) * w1; a1 += b2f(u1.x >> 16) * w1;
            a2 += b2f(u1.y & 0xffffu) * w1; a3 += b2f(u1.y >> 16) * w1;
        }
        // 1-deep residual
        for (; i < cnt; i += 4) {
            int s0 = ssrc[i];
            uint2 u0 = *(const uint2*)(xp + (size_t)s0 * 256 + l * 4);
            float w0 = sea[i * 9 + hh];
            a0 += b2f(u0.x & 0xffffu) * w0; a1 += b2f(u0.x >> 16) * w0;
            a2 += b2f(u0.y & 0xffffu) * w0; a3 += b2f(u0.y >> 16) * w0;
        }
        __syncthreads();
    }
    racc[wave][l][0] = a0; racc[wave][l][1] = a1;
    racc[wave][l][2] = a2; racc[wave][l][3] = a3;
    if (wave == 0) {
#pragma unroll
        for (int off = 32; off > 0; off >>= 1) {
#pragma unroll
            for (int j = 0; j < 8; j++) den[j] += __shfl_xor(den[j], off, 64);
        }
        if (l < 8) rden[l] = den[l];
    }
    __syncthreads();
    if (wave != 0) return;  // no further barriers below
    float m0 = racc[0][l][0] + racc[1][l][0] + racc[2][l][0] + racc[3][l][0];
    float m1 = racc[0][l][1] + racc[1][l][1] + racc[2][l][1] + racc[3][l][1];
    float m2 = racc[0][l][2] + racc[1][l][2] + racc[2][l][2] + racc[3][l][2];
    float m3 = racc[0][l][3] + racc[1][l][3] + racc[2][l][3] + racc[3][l][3];
    float sinv = 1.0f / (rden[hh] + 1e-16f);
    m0 *= sinv; m1 *= sinv; m2 *= sinv; m3 *= sinv;
    float4 xv = *(const float4*)(xin + (size_t)n * 256 + l * 4);
    float4 bv = *(const float4*)(bias + l * 4);
    float y0 = xv.x + m0 + bv.x;
    float y1 = xv.y + m1 + bv.y;
    float y2 = xv.z + m2 + bv.z;
    float y3 = xv.w + m3 + bv.w;
    float s1 = y0 + y1 + y2 + y3;
    float s2 = y0 * y0 + y1 * y1 + y2 * y2 + y3 * y3;
#pragma unroll
    for (int o = 32; o > 0; o >>= 1) {
        s1 += __shfl_down(s1, o, 64);
        s2 += __shfl_down(s2, o, 64);
    }
    s1 = __shfl(s1, 0, 64); s2 = __shfl(s2, 0, 64);
    float mu = s1 * (1.f / 256.f);
    float var = s2 * (1.f / 256.f) - mu * mu;
    float rs = rsqrtf(var + LN_EPS);
    float4 gv  = *(const float4*)(gamma + l * 4);
    float4 btv = *(const float4*)(beta + l * 4);
    float4 ov;
    ov.x = (y0 - mu) * rs * gv.x + btv.x;
    ov.y = (y1 - mu) * rs * gv.y + btv.y;
    ov.z = (y2 - mu) * rs * gv.z + btv.z;
    ov.w = (y3 - mu) * rs * gv.w + btv.w;
    *(float4*)(out + (size_t)n * 256 + l * 4) = ov;
}

extern "C" void kernel_launch(void* const* d_in, const int* in_sizes, int n_in,
                              void* d_out, int out_size, void* d_ws, size_t ws_size,
                              hipStream_t stream) {
    const float* x     = (const float*)d_in[0];
    const int*   ei    = (const int*)d_in[1];
    const float* eattr = (const float*)d_in[2];
    const float* W     = (const float*)d_in[3];
    const float* We    = (const float*)d_in[4];
    const float* atts  = (const float*)d_in[5];
    const float* attd  = (const float*)d_in[6];
    const float* atte  = (const float*)d_in[7];
    const float* bias  = (const float*)d_in[8];
    const float* gamma = (const float*)d_in[9];
    const float* beta  = (const float*)d_in[10];
    float* out = (float*)d_out;
    int N = in_sizes[0] / 256;
    int E = in_sizes[1] / 2;

    char* p = (char*)d_ws;
    auto carve = [&](size_t bytes) -> void* {
        void* r = (void*)p; p += (bytes + 255) & ~(size_t)255; return r;
    };
    unsigned short* xp = (unsigned short*)carve((size_t)N * 256 * 2);  // bf16
    uint4* eav         = (uint4*)carve((size_t)E * 16);    // packed exp records (CSR order)
    int*   srcs        = (int*)carve((size_t)E * 4);       // src per CSR slot
    float* a_src       = (float*)carve((size_t)N * 8 * 4);
    float* a_dst       = (float*)carve((size_t)N * 8 * 4);
    int*   deg         = (int*)carve((size_t)N * 4);
    int*   rowptr      = (int*)carve((size_t)(N + 1) * 4);
    int*   cursor      = (int*)carve((size_t)N * 4);
    int*   bsum        = (int*)carve(1024);
    int*   boff        = (int*)carve(1024);
    float* u_src       = (float*)carve(2048 * 4);
    float* u_dst       = (float*)carve(2048 * 4);
    float* vW          = (float*)carve(512 * 4);
    unsigned short* Wf = (unsigned short*)carve(65536 * 2);

    hipMemsetAsync(deg, 0, (size_t)N * 4, stream);

    hipLaunchKernelGGL(k0a_prep, dim3(1), dim3(256), 0, stream,
                       W, We, atts, attd, atte, u_src, u_dst, vW);
    hipLaunchKernelGGL(k0b_wfrag, dim3(256), dim3(256), 0, stream, W, Wf);
    hipLaunchKernelGGL(k_deg, dim3((E + 255) / 256), dim3(256), 0, stream, ei, deg, E);
    int nb = (N + 1023) / 1024;
    hipLaunchKernelGGL(k3a_scan, dim3(nb), dim3(1024), 0, stream, deg, rowptr, bsum, N);
    hipLaunchKernelGGL(k3b_scan, dim3(1), dim3(64), 0, stream, bsum, boff, nb);
    hipLaunchKernelGGL(k3c_add, dim3(nb), dim3(1024), 0, stream, rowptr, cursor, boff, N, E);
    hipLaunchKernelGGL(k1_xp, dim3((N + 15) / 16), dim3(256), 0, stream,
                       x, Wf, u_src, u_dst, xp, a_src, a_dst, N);
    hipLaunchKernelGGL(k2_edge, dim3((E + 63) / 64), dim3(256), 0, stream,
                       ei, eattr, vW, a_src, a_dst, cursor, srcs, eav, E);
    hipLaunchKernelGGL(k4_agg, dim3(N), dim3(256), 0, stream,
                       x, xp, srcs, eav, rowptr, bias, gamma, beta, out, N);
}

// Round 5
// 545.633 us; speedup vs baseline: 1.1409x; 1.1190x over previous
//
#include <hip/hip_runtime.h>
#include <cstdint>

#define NEG_SLOPE 0.2f
#define LN_EPS 1e-5f

typedef __bf16 bf16x8 __attribute__((ext_vector_type(8)));
typedef float f32x4 __attribute__((ext_vector_type(4)));

__device__ __forceinline__ float b2f(unsigned int u) {
    union { unsigned int i; float f; } x; x.i = u << 16; return x.f;
}
__device__ __forceinline__ unsigned short f2b(float f) {
    union { float f; unsigned int i; } x; x.f = f;
    unsigned int r = x.i + 0x7fffu + ((x.i >> 16) & 1u);
    return (unsigned short)(r >> 16);
}
// hardware bf16 convert (compiler pairs into v_cvt_pk_bf16_f32, RNE)
__device__ __forceinline__ unsigned short f2b_hw(float f) {
    __bf16 b = (__bf16)f;
    union { __bf16 b; unsigned short u; } x; x.b = b; return x.u;
}

// ---------------- k0_prep: fused deg-histogram + Wf fragment layout + vW ----------
__global__ __launch_bounds__(256) void k0_prep(const int* __restrict__ ei,
                                               const float* __restrict__ W,
                                               const float* __restrict__ We,
                                               const float* __restrict__ att_edge,
                                               int* __restrict__ deg,
                                               unsigned short* __restrict__ Wf,
                                               float* __restrict__ vW,
                                               int E, int nDegBlocks) {
    int b = blockIdx.x;
    if (b < nDegBlocks) {
        int e = b * 256 + threadIdx.x;
        if (e < E) atomicAdd(deg + ei[E + e], 1);
    } else if (b < nDegBlocks + 256) {
        // Wf flat index T = ((((w*4+i)*8+kk)*64)+lane)*8 + j
        int T = (b - nDegBlocks) * 256 + threadIdx.x;  // 65536 total
        int j    = T & 7;
        int lane = (T >> 3) & 63;
        int kk   = (T >> 9) & 7;
        int i    = (T >> 12) & 3;
        int w    = T >> 14;
        int n = w * 64 + i * 16 + (lane & 15);
        int k = kk * 32 + (lane >> 4) * 8 + j;
        Wf[T] = f2b(W[k * 256 + n]);
    } else {
        int t = threadIdx.x;
        if (t < 64) {
            const float* er = We + t * 256;
            for (int h = 0; h < 8; h++) {
                float s = 0.f;
                for (int c = 0; c < 32; c++) s += er[h * 32 + c] * att_edge[h * 32 + c];
                vW[t * 8 + h] = s;
            }
        }
    }
}

// ---------------- k1: xp = bf16(x) @ bf16(W) via MFMA, M=64 tile ------------------
// B-frags reused across 4 A row-groups; a_src/a_dst computed in epilogue from acc.
__global__ __launch_bounds__(256) void k1_xp(const float* __restrict__ x,
                                             const unsigned short* __restrict__ Wf,
                                             const float* __restrict__ att_src,
                                             const float* __restrict__ att_dst,
                                             unsigned short* __restrict__ xp,
                                             float* __restrict__ a_src,
                                             float* __restrict__ a_dst, int N) {
    int m0 = blockIdx.x * 64;
    int lane = threadIdx.x & 63, wave = threadIdx.x >> 6;
    int quad = lane >> 4, l16 = lane & 15;
    const unsigned short* wfw = Wf + (size_t)wave * 16384;
    const float* ap[4];
#pragma unroll
    for (int g = 0; g < 4; g++) {
        int mrow = m0 + g * 16 + l16; if (mrow > N - 1) mrow = N - 1;
        ap[g] = x + (size_t)mrow * 256 + quad * 8;
    }
    f32x4 acc[4][4];
#pragma unroll
    for (int g = 0; g < 4; g++)
#pragma unroll
        for (int i = 0; i < 4; i++) acc[g][i] = (f32x4){0, 0, 0, 0};

#pragma unroll
    for (int kk = 0; kk < 8; kk++) {
        const unsigned short* wk = wfw + kk * 512 + lane * 8;  // coalesced 1KB/wave
        bf16x8 b0 = *(const bf16x8*)(wk);
        bf16x8 b1 = *(const bf16x8*)(wk + 4096);
        bf16x8 b2 = *(const bf16x8*)(wk + 8192);
        bf16x8 b3 = *(const bf16x8*)(wk + 12288);
#pragma unroll
        for (int g = 0; g < 4; g++) {
            float4 fa0 = *(const float4*)(ap[g] + kk * 32);
            float4 fa1 = *(const float4*)(ap[g] + kk * 32 + 4);
            bf16x8 Av;
            Av[0] = (__bf16)fa0.x; Av[1] = (__bf16)fa0.y;
            Av[2] = (__bf16)fa0.z; Av[3] = (__bf16)fa0.w;
            Av[4] = (__bf16)fa1.x; Av[5] = (__bf16)fa1.y;
            Av[6] = (__bf16)fa1.z; Av[7] = (__bf16)fa1.w;
            acc[g][0] = __builtin_amdgcn_mfma_f32_16x16x32_bf16(Av, b0, acc[g][0], 0, 0, 0);
            acc[g][1] = __builtin_amdgcn_mfma_f32_16x16x32_bf16(Av, b1, acc[g][1], 0, 0, 0);
            acc[g][2] = __builtin_amdgcn_mfma_f32_16x16x32_bf16(Av, b2, acc[g][2], 0, 0, 0);
            acc[g][3] = __builtin_amdgcn_mfma_f32_16x16x32_bf16(Av, b3, acc[g][3], 0, 0, 0);
        }
    }

    // ---- store xp (bf16) -------------------------------------------------------
    int nb = wave * 64;
#pragma unroll
    for (int g = 0; g < 4; g++) {
#pragma unroll
        for (int r = 0; r < 4; r++) {
            int m = m0 + g * 16 + quad * 4 + r;
            if (m < N) {
                unsigned short* op = xp + (size_t)m * 256 + nb + l16;
                op[0]  = f2b_hw(acc[g][0][r]); op[16] = f2b_hw(acc[g][1][r]);
                op[32] = f2b_hw(acc[g][2][r]); op[48] = f2b_hw(acc[g][3][r]);
            }
        }
    }

    // ---- epilogue fold: a_src/a_dst from accumulators --------------------------
    // col = wave*64 + i*16 + l16 -> head h = wave*2 + (i>>1), c' = (i&1)*16 + l16
    float asv[4], adv[4];
#pragma unroll
    for (int i = 0; i < 4; i++) {
        int h = wave * 2 + (i >> 1);
        int c = (i & 1) * 16 + l16;
        asv[i] = att_src[h * 32 + c];
        adv[i] = att_dst[h * 32 + c];
    }
#pragma unroll
    for (int g = 0; g < 4; g++) {
#pragma unroll
        for (int hb = 0; hb < 2; hb++) {
            f32x4 ps = {0, 0, 0, 0}, pd = {0, 0, 0, 0};
#pragma unroll
            for (int ii = 0; ii < 2; ii++) {
                int i = hb * 2 + ii;
#pragma unroll
                for (int r = 0; r < 4; r++) {
                    ps[r] += acc[g][i][r] * asv[i];
                    pd[r] += acc[g][i][r] * adv[i];
                }
            }
            // reduce over the 16 lanes of the quad (l16 axis)
#pragma unroll
            for (int off = 1; off < 16; off <<= 1) {
#pragma unroll
                for (int r = 0; r < 4; r++) {
                    ps[r] += __shfl_xor(ps[r], off, 64);
                    pd[r] += __shfl_xor(pd[r], off, 64);
                }
            }
            if (l16 == 0) {
                int h = wave * 2 + hb;
#pragma unroll
                for (int r = 0; r < 4; r++) {
                    int m = m0 + g * 16 + quad * 4 + r;
                    if (m < N) {
                        a_src[(size_t)m * 8 + h] = ps[r];
                        a_dst[(size_t)m * 8 + h] = pd[r];
                    }
                }
            }
        }
    }
}

// ---------------- k2: per-edge logits + exp; scatter packed CSR records -----------
__global__ __launch_bounds__(256) void k2_edge(const int* __restrict__ ei,
                                               const float* __restrict__ eattr,
                                               const float* __restrict__ vW,
                                               const float* __restrict__ a_src,
                                               const float* __restrict__ a_dst,
                                               int* __restrict__ cursor,
                                               int* __restrict__ srcs,
                                               uint4* __restrict__ eav, int E) {
    __shared__ float sv[2048];  // vW bank-permuted: row kl = ((k&15)<<2)|(k>>4)
    int t = threadIdx.x;
    if (t < 128) {  // vW = 64 rows x 8 heads = 128 float4s
        const float4* g = (const float4*)vW;
        float4* s4 = (float4*)sv;
        int k = t >> 1, half = t & 1;
        int kl = ((k & 15) << 2) | (k >> 4);
        s4[kl * 2 + half] = g[t];
    }
    __syncthreads();
    int e = blockIdx.x * 64 + (t >> 2), kp = t & 3;
    if (e >= E) return;
    const float4* ar = (const float4*)(eattr + (size_t)e * 64 + kp * 16);
    float acc[8] = {0,0,0,0,0,0,0,0};
#pragma unroll
    for (int q = 0; q < 4; q++) {
        float4 u = ar[q];
        float f[4] = {u.x, u.y, u.z, u.w};
#pragma unroll
        for (int j = 0; j < 4; j++) {
            int kl = ((q * 4 + j) << 2) | kp;
            const float4* vp = (const float4*)(sv + kl * 8);
            float4 v0 = vp[0], v1 = vp[1];
            acc[0] += f[j] * v0.x; acc[1] += f[j] * v0.y;
            acc[2] += f[j] * v0.z; acc[3] += f[j] * v0.w;
            acc[4] += f[j] * v1.x; acc[5] += f[j] * v1.y;
            acc[6] += f[j] * v1.z; acc[7] += f[j] * v1.w;
        }
    }
#pragma unroll
    for (int h = 0; h < 8; h++) {
        acc[h] += __shfl_xor(acc[h], 1, 64);
        acc[h] += __shfl_xor(acc[h], 2, 64);
    }
    int s = ei[e], d = ei[E + e];
    float2 asv = *(const float2*)(a_src + s * 8 + kp * 2);
    float2 adv = *(const float2*)(a_dst + d * 8 + kp * 2);
    float l0 = asv.x + adv.x + acc[kp * 2];
    float l1 = asv.y + adv.y + acc[kp * 2 + 1];
    l0 = (l0 > 0.f) ? l0 : NEG_SLOPE * l0;
    l1 = (l1 > 0.f) ? l1 : NEG_SLOPE * l1;
    unsigned int pk = (unsigned)f2b(__expf(l0)) | ((unsigned)f2b(__expf(l1)) << 16);
    int l = t & 63;
    int p = 0;
    if (kp == 0) p = atomicAdd(cursor + d, 1);
    p = __shfl(p, l & 60, 64);              // broadcast slot within 4-lane group
    ((unsigned int*)eav)[(size_t)p * 4 + kp] = pk;
    if (kp == 0) srcs[p] = s;
}

// ---------------- k3: 3-phase exclusive scan of degrees -> CSR rowptr --------------
__global__ __launch_bounds__(1024) void k3a_scan(const int* __restrict__ deg,
                                                 int* __restrict__ rowptr,
                                                 int* __restrict__ bsum, int N) {
    __shared__ int s[1024];
    int t = threadIdx.x, i = blockIdx.x * 1024 + t;
    int v = (i < N) ? deg[i] : 0;
    s[t] = v; __syncthreads();
    for (int off = 1; off < 1024; off <<= 1) {
        int add = (t >= off) ? s[t - off] : 0;
        __syncthreads();
        s[t] += add;
        __syncthreads();
    }
    if (i < N) rowptr[i] = s[t] - v;
    if (t == 1023) bsum[blockIdx.x] = s[1023];
}
// parallel wave scan (nb <= 64)
__global__ void k3b_scan(const int* __restrict__ bsum, int* __restrict__ boff, int nb) {
    int l = threadIdx.x;  // 64
    int v = (l < nb) ? bsum[l] : 0;
    int x = v;
#pragma unroll
    for (int off = 1; off < 64; off <<= 1) {
        int y = __shfl_up(x, off, 64);
        if (l >= off) x += y;
    }
    if (l < nb) boff[l] = x - v;
}
__global__ __launch_bounds__(1024) void k3c_add(int* __restrict__ rowptr,
                                                int* __restrict__ cursor,
                                                const int* __restrict__ boff, int N, int E) {
    int i = blockIdx.x * 1024 + threadIdx.x;
    if (i < N) {
        int r = rowptr[i] + boff[blockIdx.x];
        rowptr[i] = r; cursor[i] = r;
    }
    if (i == 0) rowptr[N] = E;
}

// ---------------- k4: sequential staged records + 4-deep unrolled gather + LN -----
__global__ __launch_bounds__(256) void k4_agg(const float* __restrict__ xin,
                                              const unsigned short* __restrict__ xp,
                                              const int* __restrict__ srcs,
                                              const uint4* __restrict__ eav,
                                              const int* __restrict__ rowptr,
                                              const float* __restrict__ bias,
                                              const float* __restrict__ gamma,
                                              const float* __restrict__ beta,
                                              float* __restrict__ out, int N) {
    __shared__ int ssrc[64];
    __shared__ float sea[64 * 9];       // raw exp values, pad 8->9
    __shared__ float racc[4][64][4];    // per-wave partial messages
    __shared__ float rden[8];
    int n = blockIdx.x;
    int t = threadIdx.x, wave = t >> 6, l = t & 63;
    int start = rowptr[n], end = rowptr[n + 1];
    int hh = l >> 3;
    float a0 = 0.f, a1 = 0.f, a2 = 0.f, a3 = 0.f;
    float den[8] = {0,0,0,0,0,0,0,0};   // only wave-0 lanes (t<cnt<=64) accumulate
    for (int base = start; base < end; base += 64) {
        int cnt = end - base; if (cnt > 64) cnt = 64;
        if (t < cnt) {
            ssrc[t] = srcs[base + t];              // coalesced
            uint4 u = eav[base + t];               // coalesced
            float v0 = b2f(u.x & 0xffffu), v1 = b2f(u.x >> 16);
            float v2 = b2f(u.y & 0xffffu), v3 = b2f(u.y >> 16);
            float v4 = b2f(u.z & 0xffffu), v5 = b2f(u.z >> 16);
            float v6 = b2f(u.w & 0xffffu), v7 = b2f(u.w >> 16);
            float* sp = sea + t * 9;
            sp[0] = v0; sp[1] = v1; sp[2] = v2; sp[3] = v3;
            sp[4] = v4; sp[5] = v5; sp[6] = v6; sp[7] = v7;
            den[0] += v0; den[1] += v1; den[2] += v2; den[3] += v3;
            den[4] += v4; den[5] += v5; den[6] += v6; den[7] += v7;
        }
        __syncthreads();
        int i = wave;
        for (; i + 12 < cnt; i += 16) {
            int s0 = ssrc[i], s1 = ssrc[i + 4], s2 = ssrc[i + 8], s3 = ssrc[i + 12];
            uint2 u0 = *(const uint2*)(xp + (size_t)s0 * 256 + l * 4);
            uint2 u1 = *(const uint2*)(xp + (size_t)s1 * 256 + l * 4);
            uint2 u2 = *(const uint2*)(xp + (size_t)s2 * 256 + l * 4);
            uint2 u3 = *(const uint2*)(xp + (size_t)s3 * 256 + l * 4);
            float w0 = sea[i * 9 + hh],        w1 = sea[(i + 4) * 9 + hh];
            float w2 = sea[(i + 8) * 9 + hh],  w3 = sea[(i + 12) * 9 + hh];
            a0 += b2f(u0.x & 0xffffu) * w0; a1 += b2f(u0.x >> 16) * w0;
            a2 += b2f(u0.y & 0xffffu) * w0; a3 += b2f(u0.y >> 16) * w0;
            a0 += b2f(u1.x & 0xffffu) * w1; a1 += b2f(u1.x >> 16) * w1;
            a2 += b2f(u1.y & 0xffffu) * w1; a3 += b2f(u1.y >> 16) * w1;
            a0 += b2f(u2.x & 0xffffu) * w2; a1 += b2f(u2.x >> 16) * w2;
            a2 += b2f(u2.y & 0xffffu) * w2; a3 += b2f(u2.y >> 16) * w2;
            a0 += b2f(u3.x & 0xffffu) * w3; a1 += b2f(u3.x >> 16) * w3;
            a2 += b2f(u3.y & 0xffffu) * w3; a3 += b2f(u3.y >> 16) * w3;
        }
        for (; i + 4 < cnt; i += 8) {
            int s0 = ssrc[i], s1 = ssrc[i + 4];
            uint2 u0 = *(const uint2*)(xp + (size_t)s0 * 256 + l * 4);
            uint2 u1 = *(const uint2*)(xp + (size_t)s1 * 256 + l * 4);
            float w0 = sea[i * 9 + hh], w1 = sea[(i + 4) * 9 + hh];
            a0 += b2f(u0.x & 0xffffu) * w0; a1 += b2f(u0.x >> 16) * w0;
            a2 += b2f(u0.y & 0xffffu) * w0; a3 += b2f(u0.y >> 16) * w0;
            a0 += b2f(u1.x & 0xffffu) * w1; a1 += b2f(u1.x >> 16) * w1;
            a2 += b2f(u1.y & 0xffffu) * w1; a3 += b2f(u1.y >> 16) * w1;
        }
        for (; i < cnt; i += 4) {
            int s0 = ssrc[i];
            uint2 u0 = *(const uint2*)(xp + (size_t)s0 * 256 + l * 4);
            float w0 = sea[i * 9 + hh];
            a0 += b2f(u0.x & 0xffffu) * w0; a1 += b2f(u0.x >> 16) * w0;
            a2 += b2f(u0.y & 0xffffu) * w0; a3 += b2f(u0.y >> 16) * w0;
        }
        __syncthreads();
    }
    racc[wave][l][0] = a0; racc[wave][l][1] = a1;
    racc[wave][l][2] = a2; racc[wave][l][3] = a3;
    if (wave == 0) {
#pragma unroll
        for (int off = 32; off > 0; off >>= 1) {
#pragma unroll
            for (int j = 0; j < 8; j++) den[j] += __shfl_xor(den[j], off, 64);
        }
        if (l < 8) rden[l] = den[l];
    }
    __syncthreads();
    if (wave != 0) return;  // no further barriers below
    float m0 = racc[0][l][0] + racc[1][l][0] + racc[2][l][0] + racc[3][l][0];
    float m1 = racc[0][l][1] + racc[1][l][1] + racc[2][l][1] + racc[3][l][1];
    float m2 = racc[0][l][2] + racc[1][l][2] + racc[2][l][2] + racc[3][l][2];
    float m3 = racc[0][l][3] + racc[1][l][3] + racc[2][l][3] + racc[3][l][3];
    float sinv = 1.0f / (rden[hh] + 1e-16f);
    m0 *= sinv; m1 *= sinv; m2 *= sinv; m3 *= sinv;
    float4 xv = *(const float4*)(xin + (size_t)n * 256 + l * 4);
    float4 bv = *(const float4*)(bias + l * 4);
    float y0 = xv.x + m0 + bv.x;
    float y1 = xv.y + m1 + bv.y;
    float y2 = xv.z + m2 + bv.z;
    float y3 = xv.w + m3 + bv.w;
    float s1 = y0 + y1 + y2 + y3;
    float s2 = y0 * y0 + y1 * y1 + y2 * y2 + y3 * y3;
#pragma unroll
    for (int o = 32; o > 0; o >>= 1) {
        s1 += __shfl_down(s1, o, 64);
        s2 += __shfl_down(s2, o, 64);
    }
    s1 = __shfl(s1, 0, 64); s2 = __shfl(s2, 0, 64);
    float mu = s1 * (1.f / 256.f);
    float var = s2 * (1.f / 256.f) - mu * mu;
    float rs = rsqrtf(var + LN_EPS);
    float4 gv  = *(const float4*)(gamma + l * 4);
    float4 btv = *(const float4*)(beta + l * 4);
    float4 ov;
    ov.x = (y0 - mu) * rs * gv.x + btv.x;
    ov.y = (y1 - mu) * rs * gv.y + btv.y;
    ov.z = (y2 - mu) * rs * gv.z + btv.z;
    ov.w = (y3 - mu) * rs * gv.w + btv.w;
    *(float4*)(out + (size_t)n * 256 + l * 4) = ov;
}

extern "C" void kernel_launch(void* const* d_in, const int* in_sizes, int n_in,
                              void* d_out, int out_size, void* d_ws, size_t ws_size,
                              hipStream_t stream) {
    const float* x     = (const float*)d_in[0];
    const int*   ei    = (const int*)d_in[1];
    const float* eattr = (const float*)d_in[2];
    const float* W     = (const float*)d_in[3];
    const float* We    = (const float*)d_in[4];
    const float* atts  = (const float*)d_in[5];
    const float* attd  = (const float*)d_in[6];
    const float* atte  = (const float*)d_in[7];
    const float* bias  = (const float*)d_in[8];
    const float* gamma = (const float*)d_in[9];
    const float* beta  = (const float*)d_in[10];
    float* out = (float*)d_out;
    int N = in_sizes[0] / 256;
    int E = in_sizes[1] / 2;

    char* p = (char*)d_ws;
    auto carve = [&](size_t bytes) -> void* {
        void* r = (void*)p; p += (bytes + 255) & ~(size_t)255; return r;
    };
    unsigned short* xp = (unsigned short*)carve((size_t)N * 256 * 2);  // bf16
    uint4* eav         = (uint4*)carve((size_t)E * 16);    // packed exp records (CSR order)
    int*   srcs        = (int*)carve((size_t)E * 4);       // src per CSR slot
    float* a_src       = (float*)carve((size_t)N * 8 * 4);
    float* a_dst       = (float*)carve((size_t)N * 8 * 4);
    int*   deg         = (int*)carve((size_t)N * 4);
    int*   rowptr      = (int*)carve((size_t)(N + 1) * 4);
    int*   cursor      = (int*)carve((size_t)N * 4);
    int*   bsum        = (int*)carve(1024);
    int*   boff        = (int*)carve(1024);
    float* vW          = (float*)carve(512 * 4);
    unsigned short* Wf = (unsigned short*)carve(65536 * 2);

    hipMemsetAsync(deg, 0, (size_t)N * 4, stream);

    int nDeg = (E + 255) / 256;
    hipLaunchKernelGGL(k0_prep, dim3(nDeg + 257), dim3(256), 0, stream,
                       ei, W, We, atte, deg, Wf, vW, E, nDeg);
    int nb = (N + 1023) / 1024;
    hipLaunchKernelGGL(k3a_scan, dim3(nb), dim3(1024), 0, stream, deg, rowptr, bsum, N);
    hipLaunchKernelGGL(k3b_scan, dim3(1), dim3(64), 0, stream, bsum, boff, nb);
    hipLaunchKernelGGL(k3c_add, dim3(nb), dim3(1024), 0, stream, rowptr, cursor, boff, N, E);
    hipLaunchKernelGGL(k1_xp, dim3((N + 63) / 64), dim3(256), 0, stream,
                       x, Wf, atts, attd, xp, a_src, a_dst, N);
    hipLaunchKernelGGL(k2_edge, dim3((E + 63) / 64), dim3(256), 0, stream,
                       ei, eattr, vW, a_src, a_dst, cursor, srcs, eav, E);
    hipLaunchKernelGGL(k4_agg, dim3(N), dim3(256), 0, stream,
                       x, xp, srcs, eav, rowptr, bias, gamma, beta, out, N);
}